// Round 1
// baseline (32.487 us; speedup 1.0000x reference)
//
#include <hip/hip_runtime.h>

#define NF 17
#define ED 16
#define NN 23

__global__ __launch_bounds__(256) void ffm_fwd_kernel(
    const int* __restrict__ x_cat,
    const float* __restrict__ x_num,
    const float* __restrict__ table,
    const float* __restrict__ W_num,
    const float* __restrict__ bias,
    float* __restrict__ out,
    int nrows)
{
    // Per-block colsum of W_num: wsum[j] = sum_d W_num[d][j]
    __shared__ float wsum[NN];
    const int tid = threadIdx.x;
    if (tid < NN) {
        float a = 0.f;
        #pragma unroll
        for (int d = 0; d < ED; ++d) a += W_num[d * NN + tid];
        wsum[tid] = a;
    }
    __syncthreads();

    const int row = blockIdx.x * blockDim.x + tid;
    if (row >= nrows) return;

    // OFFSETS = exclusive cumsum of VOCAB (compile-time constants)
    const int off[NF] = {0, 500, 550, 650, 653,
                         1000653, 1000663, 1000683, 1000783, 1000785,
                         1000787, 1001788, 1001792, 1001796, 1001846,
                         1003846, 1003856};

    float s[ED];
    #pragma unroll
    for (int d = 0; d < ED; ++d) s[d] = 0.f;
    float sq = 0.f;

    const int* xc = x_cat + (long)row * NF;
    #pragma unroll
    for (int f = 0; f < NF; ++f) {
        const int idx = xc[f] + off[f];
        const float4* t = (const float4*)(table + (long)idx * ED);
        #pragma unroll
        for (int q = 0; q < 4; ++q) {
            float4 v = t[q];
            s[4*q+0] += v.x;
            s[4*q+1] += v.y;
            s[4*q+2] += v.z;
            s[4*q+3] += v.w;
            sq += v.x*v.x + v.y*v.y + v.z*v.z + v.w*v.w;
        }
    }

    // numeric-linear term: x_num . colsum(W_num)
    float lin_num = 0.f;
    const float* xn = x_num + (long)row * NN;
    #pragma unroll
    for (int j = 0; j < NN; ++j) lin_num += xn[j] * wsum[j];

    float ssum = 0.f, ss2 = 0.f;
    #pragma unroll
    for (int d = 0; d < ED; ++d) { ssum += s[d]; ss2 += s[d] * s[d]; }

    out[row] = bias[0] + ssum + lin_num + 0.5f * (ss2 - sq);
}

extern "C" void kernel_launch(void* const* d_in, const int* in_sizes, int n_in,
                              void* d_out, int out_size, void* d_ws, size_t ws_size,
                              hipStream_t stream) {
    const int*   x_cat = (const int*)  d_in[0];
    const float* x_num = (const float*)d_in[1];
    const float* table = (const float*)d_in[2];
    const float* W_num = (const float*)d_in[3];
    const float* bias  = (const float*)d_in[4];
    float* out = (float*)d_out;

    const int nrows = out_size;  // 262144
    const int block = 256;
    const int grid = (nrows + block - 1) / block;
    ffm_fwd_kernel<<<grid, block, 0, stream>>>(x_cat, x_num, table, W_num, bias, out, nrows);
}

// Round 2
// 29.551 us; speedup vs baseline: 1.0993x; 1.0993x over previous
//
#include <hip/hip_runtime.h>

#define NF 17
#define ED 16
#define NN 23
#define RPB 64     // rows per block (256 threads / 4 lanes-per-row)
#define BLK 256

__global__ __launch_bounds__(BLK) void ffm_fwd_kernel(
    const int* __restrict__ x_cat,
    const float* __restrict__ x_num,
    const float* __restrict__ table,
    const float* __restrict__ W_num,
    const float* __restrict__ bias,
    float* __restrict__ out,
    int nrows)
{
    __shared__ int   lds_cat[RPB * NF];   // 1088 ints  (4.3 KB)
    __shared__ float lds_num[RPB * NN];   // 1472 floats (5.9 KB)
    __shared__ float wsum[NN];

    const int tid = threadIdx.x;

    // colsum of W_num
    if (tid < NN) {
        float a = 0.f;
        #pragma unroll
        for (int d = 0; d < ED; ++d) a += W_num[d * NN + tid];
        wsum[tid] = a;
    }

    // Stage this block's 64 rows of x_cat and x_num, fully coalesced.
    {
        const int cbase = blockIdx.x * (RPB * NF);
        #pragma unroll
        for (int i = tid; i < RPB * NF; i += BLK) lds_cat[i] = x_cat[cbase + i];
        const int nbase = blockIdx.x * (RPB * NN);
        #pragma unroll
        for (int i = tid; i < RPB * NN; i += BLK) lds_num[i] = x_num[nbase + i];
    }
    __syncthreads();

    const int rl  = tid >> 2;            // local row 0..63
    const int g   = tid & 3;             // dim-group: owns dims [4g, 4g+4)
    const int row = blockIdx.x * RPB + rl;
    if (row >= nrows) return;

    // OFFSETS = exclusive cumsum of VOCAB
    const int off[NF] = {0, 500, 550, 650, 653,
                         1000653, 1000663, 1000683, 1000783, 1000785,
                         1000787, 1001788, 1001792, 1001796, 1001846,
                         1003846, 1003856};

    float s0 = 0.f, s1 = 0.f, s2 = 0.f, s3 = 0.f, sq = 0.f;
    #pragma unroll
    for (int f = 0; f < NF; ++f) {
        const int idx = lds_cat[rl * NF + f] + off[f];
        const float4 v = *(const float4*)(table + (size_t)idx * ED + g * 4);
        s0 += v.x; s1 += v.y; s2 += v.z; s3 += v.w;
        sq += v.x * v.x + v.y * v.y + v.z * v.z + v.w * v.w;
    }

    float lin = 0.f;
    #pragma unroll
    for (int j = g; j < NN; j += 4) lin += lds_num[rl * NN + j] * wsum[j];

    float ssum = s0 + s1 + s2 + s3;
    float ss2  = s0 * s0 + s1 * s1 + s2 * s2 + s3 * s3;

    // reduce the 4 scalars across the 4-lane group
    #pragma unroll
    for (int m = 1; m <= 2; m <<= 1) {
        ssum += __shfl_xor(ssum, m);
        ss2  += __shfl_xor(ss2, m);
        sq   += __shfl_xor(sq, m);
        lin  += __shfl_xor(lin, m);
    }

    if (g == 0) out[row] = bias[0] + ssum + lin + 0.5f * (ss2 - sq);
}

extern "C" void kernel_launch(void* const* d_in, const int* in_sizes, int n_in,
                              void* d_out, int out_size, void* d_ws, size_t ws_size,
                              hipStream_t stream) {
    const int*   x_cat = (const int*)  d_in[0];
    const float* x_num = (const float*)d_in[1];
    const float* table = (const float*)d_in[2];
    const float* W_num = (const float*)d_in[3];
    const float* bias  = (const float*)d_in[4];
    float* out = (float*)d_out;

    const int nrows = out_size;                 // 262144
    const int grid = (nrows + RPB - 1) / RPB;   // 4096
    ffm_fwd_kernel<<<grid, BLK, 0, stream>>>(x_cat, x_num, table, W_num, bias, out, nrows);
}